// Round 3
// baseline (243.870 us; speedup 1.0000x reference)
//
#include <hip/hip_runtime.h>
#include <hip/hip_cooperative_groups.h>

namespace cg = cooperative_groups;

// N = 4096 bodies, 2D. Broad phase keeps first 4N row-major AABB hits,
// exact phase keeps first N true penetrations, resolve is last-write-wins.
#define NB 4096
#define KBROAD (4 * NB)   // 16384
#define KEXACT NB         // 4096
#define NBLK 512
#define NTHR 256
typedef unsigned long long u64;

// One cooperative kernel, 5 phases, 3 grid syncs.
// LDS: rb[4096] row-base table (16 KB), reused as hb/wb in phase D.
__global__ __launch_bounds__(NTHR, 2) void fused_kernel(
    const float2* __restrict__ pos, const float* __restrict__ rad,
    u64* __restrict__ masks, int* __restrict__ row_counts,
    float2* __restrict__ penvec, unsigned* __restrict__ pij,
    unsigned* __restrict__ hitbits, float2* __restrict__ ev,
    int* __restrict__ last_i, int* __restrict__ last_j,
    float2* __restrict__ out) {
  cg::grid_group grid = cg::this_grid();
  __shared__ int rb[NB];
  __shared__ int wsum[4];
  int t = threadIdx.x;
  int wv = t >> 6, lane = t & 63;
  int gid = blockIdx.x * NTHR + t;

  // init (consumed only after grid syncs)
  if (gid < 512) hitbits[gid] = 0;
  if (gid < NB) { last_i[gid] = -1; last_j[gid] = -1; }

  // ---- Phase A: broad AABB masks + per-row counts. 2048 waves, 2 rows each.
  {
    int w = blockIdx.x * 4 + wv;        // 0..2047
    int r0 = w * 2;
    float2 p0 = pos[r0], p1 = pos[r0 + 1];
    float ra0 = rad[r0], ra1 = rad[r0 + 1];
    u64 mw0 = 0, mw1 = 0;               // lane c keeps chunk c's word
    int c0 = 0, c1 = 0;
    for (int c = 0; c < 64; ++c) {
      int j = c * 64 + lane;
      float2 pj = pos[j];
      float rj = rad[j];
      float rs0 = ra0 + rj, rs1 = ra1 + rj;
      bool h0 = (j != r0) && (fabsf(p0.x - pj.x) <= rs0) && (fabsf(p0.y - pj.y) <= rs0);
      bool h1 = (j != r0 + 1) && (fabsf(p1.x - pj.x) <= rs1) && (fabsf(p1.y - pj.y) <= rs1);
      u64 m0 = __ballot(h0), m1 = __ballot(h1);
      if (lane == c) { mw0 = m0; mw1 = m1; }
      c0 += __popcll(m0);
      c1 += __popcll(m1);
    }
    masks[(size_t)r0 * 64 + lane] = mw0;
    masks[(size_t)(r0 + 1) * 64 + lane] = mw1;
    if (lane == 0) { row_counts[r0] = c0; row_counts[r0 + 1] = c1; }
  }
  grid.sync();

  // ---- Phase B: redundant per-block exclusive scan of 4096 row counts.
  {
    int c[16], s = 0;
    #pragma unroll
    for (int k = 0; k < 16; ++k) { c[k] = row_counts[t * 16 + k]; s += c[k]; }
    int v = s;
    #pragma unroll
    for (int off = 1; off < 64; off <<= 1) {
      int u = __shfl_up(v, off);
      if (lane >= off) v += u;
    }
    if (lane == 63) wsum[wv] = v;
    __syncthreads();
    int wbase = 0;
    #pragma unroll
    for (int w2 = 0; w2 < 4; ++w2) if (w2 < wv) wbase += wsum[w2];
    int run = wbase + v - s;
    #pragma unroll
    for (int k = 0; k < 16; ++k) { rb[t * 16 + k] = run; run += c[k]; }
    __syncthreads();
  }

  // ---- Phase C: fill + inline exact circle test. 8 rows/block, 2 per wave.
  // Lane c owns chunk c: wave scan of popcounts -> per-lane base, then each
  // lane walks only its own set bits (no serial 64-chunk shuffle loop).
  for (int q = 0; q < 2; ++q) {
    int r = blockIdx.x * 8 + wv * 2 + q;
    int rowbase = rb[r];                 // uniform
    if (rowbase >= KBROAD) continue;     // uniform branch
    u64 myw = masks[(size_t)r * 64 + lane];
    int cnt = __popcll(myw);
    int v = cnt;
    #pragma unroll
    for (int off = 1; off < 64; off <<= 1) {
      int u = __shfl_up(v, off);
      if (lane >= off) v += u;
    }
    int rank = rowbase + v - cnt;        // base rank of my chunk
    if (!myw) continue;                  // per-lane; no wave ops below
    float2 pr = pos[r];
    float rr = rad[r];
    u64 m = myw;
    while (m && rank < KBROAD) {
      int b = __builtin_ctzll(m);
      m &= m - 1;
      int j = (lane << 6) + b;
      // exact circle test, rn ops to bit-match numpy (no FMA contraction)
      float2 pj = pos[j];
      float dx = pr.x - pj.x, dy = pr.y - pj.y;
      float ss = __fadd_rn(__fadd_rn(__fmul_rn(dx, dx), __fmul_rn(dy, dy)), 1e-12f);
      float dist = __fsqrt_rn(ss);
      float pen = __fsub_rn(__fadd_rn(rr, rad[j]), dist);
      if (pen > 0.0f) {
        float sc = __fdiv_rn(pen, dist);
        penvec[rank] = make_float2(__fmul_rn(dx, sc), __fmul_rn(dy, sc));
        pij[rank] = ((unsigned)r << 16) | (unsigned)j;
        atomicOr(&hitbits[rank >> 5], 1u << (rank & 31));
      }
      ++rank;
    }
  }
  grid.sync();

  // ---- Phase D: exact compaction. Redundant scan of the 512-word bitmask,
  // then thread gid handles broad slot gid (< KBROAD).
  {
    unsigned* hb = (unsigned*)rb;        // reuse LDS (words 0..511)
    int* wb = rb + 512;                  // words 512..1023
    unsigned w0 = hitbits[2 * t], w1 = hitbits[2 * t + 1];
    hb[2 * t] = w0;
    hb[2 * t + 1] = w1;
    int cnt = __popc(w0) + __popc(w1);
    int v = cnt;
    #pragma unroll
    for (int off = 1; off < 64; off <<= 1) {
      int u = __shfl_up(v, off);
      if (lane >= off) v += u;
    }
    if (lane == 63) wsum[wv] = v;
    __syncthreads();
    int wbase = 0;
    #pragma unroll
    for (int w2 = 0; w2 < 4; ++w2) if (w2 < wv) wbase += wsum[w2];
    int excl = wbase + v - cnt;
    wb[2 * t] = excl;
    wb[2 * t + 1] = excl + __popc(w0);
    __syncthreads();
    if (gid < KBROAD) {
      unsigned word = hb[gid >> 5];
      if ((word >> (gid & 31)) & 1u) {
        int rank = wb[gid >> 5] + __popc(word & ((1u << (gid & 31)) - 1u));
        if (rank < KEXACT) {
          ev[rank] = penvec[gid];
          unsigned p = pij[gid];
          atomicMax(&last_i[p >> 16], rank);
          atomicMax(&last_j[p & 0xFFFFu], rank);
        }
      }
    }
  }
  grid.sync();

  // ---- Phase E: resolve. j-scatter wins over i-scatter; both read pos[].
  if (gid < NB) {
    float2 p = pos[gid];
    int lj = last_j[gid], li = last_i[gid];
    float2 o = p;
    if (lj >= 0) {
      o.x = __fsub_rn(p.x, __fmul_rn(0.5f, ev[lj].x));
      o.y = __fsub_rn(p.y, __fmul_rn(0.5f, ev[lj].y));
    } else if (li >= 0) {
      o.x = __fadd_rn(p.x, __fmul_rn(0.5f, ev[li].x));
      o.y = __fadd_rn(p.y, __fmul_rn(0.5f, ev[li].y));
    }
    out[gid] = o;
  }
}

// ---------------------------------------------------------------------------
extern "C" void kernel_launch(void* const* d_in, const int* in_sizes, int n_in,
                              void* d_out, int out_size, void* d_ws, size_t ws_size,
                              hipStream_t stream) {
  const float2* pos = (const float2*)d_in[0];
  const float* rad = (const float*)d_in[1];
  float2* out = (float2*)d_out;

  // Workspace layout (~2.3 MB).
  u64* masks = (u64*)d_ws;                              // NB*64 u64 = 2 MB
  float2* penvec = (float2*)(masks + (size_t)NB * 64);  // KBROAD float2
  float2* ev = penvec + KBROAD;                         // KEXACT float2
  int* row_counts = (int*)(ev + KEXACT);                // NB
  unsigned* pij = (unsigned*)(row_counts + NB);         // KBROAD
  unsigned* hitbits = pij + KBROAD;                     // 512
  int* last_i = (int*)(hitbits + 512);                  // NB
  int* last_j = last_i + NB;                            // NB

  void* args[] = {(void*)&pos, (void*)&rad, (void*)&masks, (void*)&row_counts,
                  (void*)&penvec, (void*)&pij, (void*)&hitbits, (void*)&ev,
                  (void*)&last_i, (void*)&last_j, (void*)&out};
  hipLaunchCooperativeKernel((const void*)fused_kernel, dim3(NBLK), dim3(NTHR),
                             args, 0, stream);
}

// Round 4
// 96.588 us; speedup vs baseline: 2.5249x; 2.5249x over previous
//
#include <hip/hip_runtime.h>

// N = 4096 bodies, 2D. Broad phase keeps first 4N row-major AABB hits,
// exact phase keeps first N true penetrations, resolve is last-write-wins.
#define NB 4096
#define KBROAD (4 * NB)   // 16384
#define KEXACT NB         // 4096
typedef unsigned long long u64;

// ---------------------------------------------------------------------------
// K1: broad-phase counts + per-row hit bitmasks. 2 rows per wave.
// Also zero-inits hitbits and last_i/last_j (ws is 0xAA-poisoned).
// Grid: 512 blocks x 256 threads = 2048 waves.
// ---------------------------------------------------------------------------
__global__ __launch_bounds__(256) void count_kernel(
    const float2* __restrict__ pos, const float* __restrict__ rad,
    int* __restrict__ row_counts, u64* __restrict__ masks,
    unsigned* __restrict__ hitbits, int* __restrict__ last_i,
    int* __restrict__ last_j) {
  int gid = blockIdx.x * blockDim.x + threadIdx.x;
  if (gid < 512) hitbits[gid] = 0;
  if (gid < NB) { last_i[gid] = -1; last_j[gid] = -1; }
  int wave = gid >> 6;
  int lane = gid & 63;
  int r0 = wave * 2;          // rows r0, r0+1
  float2 p0 = pos[r0], p1 = pos[r0 + 1];
  float ra0 = rad[r0], ra1 = rad[r0 + 1];
  u64 mw0 = 0, mw1 = 0;       // lane c keeps the mask word of chunk c
  int c0 = 0, c1 = 0;
  for (int c = 0; c < 64; ++c) {
    int j = c * 64 + lane;
    float2 pj = pos[j];
    float rj = rad[j];
    float rs0 = ra0 + rj, rs1 = ra1 + rj;
    bool h0 = (j != r0) && (fabsf(p0.x - pj.x) <= rs0) && (fabsf(p0.y - pj.y) <= rs0);
    bool h1 = (j != r0 + 1) && (fabsf(p1.x - pj.x) <= rs1) && (fabsf(p1.y - pj.y) <= rs1);
    u64 m0 = __ballot(h0);
    u64 m1 = __ballot(h1);
    if (lane == c) { mw0 = m0; mw1 = m1; }
    c0 += __popcll(m0);
    c1 += __popcll(m1);
  }
  masks[(size_t)r0 * 64 + lane] = mw0;          // coalesced 512 B per row
  masks[(size_t)(r0 + 1) * 64 + lane] = mw1;
  if (lane == 0) { row_counts[r0] = c0; row_counts[r0 + 1] = c1; }
}

// ---------------------------------------------------------------------------
// K2: redundant per-block exclusive scan of row counts, then fill this
// block's 16 rows from stored masks with the per-lane bit-walk, running the
// exact circle test inline. Writes penvec[slot], packed (i,j), and the
// 16384-bit exact-hit bitmask.
// Grid: 256 blocks x 256 threads (wave w owns rows blk*16 + w*4 .. +3).
// rb is stored TRANSPOSED (rb[k*256+t] = base of row t*16+k) so the 16
// scan writes per thread are stride-1 across the wave (no bank conflicts).
// ---------------------------------------------------------------------------
__global__ __launch_bounds__(256) void fill_kernel(
    const float2* __restrict__ pos, const float* __restrict__ rad,
    const int* __restrict__ row_counts, const u64* __restrict__ masks,
    float2* __restrict__ penvec, unsigned* __restrict__ pij,
    unsigned* __restrict__ hitbits) {
  __shared__ int rb[NB];     // transposed row-base table (16 KB)
  __shared__ int wsum[4];
  int t = threadIdx.x;
  int wv = t >> 6, lane = t & 63;
  // ---- stage 1: exclusive scan of 4096 counts (redundant per block).
  int c[16], s = 0;
  #pragma unroll
  for (int k = 0; k < 16; ++k) { c[k] = row_counts[t * 16 + k]; s += c[k]; }
  int v = s;  // wave inclusive scan
  #pragma unroll
  for (int off = 1; off < 64; off <<= 1) {
    int u = __shfl_up(v, off);
    if (lane >= off) v += u;
  }
  if (lane == 63) wsum[wv] = v;
  __syncthreads();
  int wbase = 0;
  #pragma unroll
  for (int w = 0; w < 4; ++w) if (w < wv) wbase += wsum[w];
  int run = wbase + v - s;   // exclusive base of thread t's first row
  #pragma unroll
  for (int k = 0; k < 16; ++k) { rb[k * 256 + t] = run; run += c[k]; }
  __syncthreads();
  // ---- stage 2: fill 4 rows per wave, lane c owns chunk c of the row.
  for (int q = 0; q < 4; ++q) {
    int r = blockIdx.x * 16 + wv * 4 + q;
    int rowbase = rb[(r & 15) * 256 + (r >> 4)];   // uniform across wave
    if (rowbase >= KBROAD) continue;               // uniform branch
    u64 myw = masks[(size_t)r * 64 + lane];
    int cnt = __popcll(myw);
    int v2 = cnt;
    #pragma unroll
    for (int off = 1; off < 64; off <<= 1) {
      int u = __shfl_up(v2, off);
      if (lane >= off) v2 += u;
    }
    int rank = rowbase + v2 - cnt;                 // base rank of my chunk
    if (!myw) continue;                            // per-lane; no wave ops below
    float2 pr = pos[r];
    float rr = rad[r];
    u64 m = myw;
    while (m && rank < KBROAD) {
      int b = __builtin_ctzll(m);
      m &= m - 1;
      int j = (lane << 6) + b;
      // exact circle test, rn ops to bit-match numpy (no FMA contraction)
      float2 pj = pos[j];
      float dx = pr.x - pj.x, dy = pr.y - pj.y;
      float ss = __fadd_rn(__fadd_rn(__fmul_rn(dx, dx), __fmul_rn(dy, dy)), 1e-12f);
      float dist = __fsqrt_rn(ss);
      float pen = __fsub_rn(__fadd_rn(rr, rad[j]), dist);
      if (pen > 0.0f) {
        float sc = __fdiv_rn(pen, dist);
        penvec[rank] = make_float2(__fmul_rn(dx, sc), __fmul_rn(dy, sc));
        pij[rank] = ((unsigned)r << 16) | (unsigned)j;
        atomicOr(&hitbits[rank >> 5], 1u << (rank & 31));
      }
      ++rank;
    }
  }
}

// ---------------------------------------------------------------------------
// K3: exact compaction. Each block redundantly popcount-scans the 512-word
// hit bitmask (2 block barriers), then its 256 threads place candidates
// s = blk*256 + t: ev[rank] = penvec[s]; last-writer via atomicMax.
// Grid: 64 blocks x 256 threads.
// ---------------------------------------------------------------------------
__global__ __launch_bounds__(256) void exact_kernel(
    const unsigned* __restrict__ hitbits, const unsigned* __restrict__ pij,
    const float2* __restrict__ penvec, float2* __restrict__ ev,
    int* __restrict__ last_i, int* __restrict__ last_j) {
  __shared__ unsigned hb[512];
  __shared__ int wb[512];
  __shared__ int wsum[4];
  int t = threadIdx.x;
  int wv = t >> 6, lane = t & 63;
  unsigned w0 = hitbits[2 * t], w1 = hitbits[2 * t + 1];
  hb[2 * t] = w0;
  hb[2 * t + 1] = w1;
  int cnt = __popc(w0) + __popc(w1);
  int v = cnt;
  #pragma unroll
  for (int off = 1; off < 64; off <<= 1) {
    int u = __shfl_up(v, off);
    if (lane >= off) v += u;
  }
  if (lane == 63) wsum[wv] = v;
  __syncthreads();
  int wbase = 0;
  #pragma unroll
  for (int w = 0; w < 4; ++w) if (w < wv) wbase += wsum[w];
  int excl = wbase + v - cnt;
  wb[2 * t] = excl;
  wb[2 * t + 1] = excl + __popc(w0);
  __syncthreads();
  int s = blockIdx.x * 256 + t;
  unsigned word = hb[s >> 5];
  if ((word >> (s & 31)) & 1u) {
    int rank = wb[s >> 5] + __popc(word & ((1u << (s & 31)) - 1u));
    if (rank < KEXACT) {
      ev[rank] = penvec[s];
      unsigned p = pij[s];
      atomicMax(&last_i[p >> 16], rank);
      atomicMax(&last_j[p & 0xFFFFu], rank);
    }
  }
}

// ---------------------------------------------------------------------------
// K4: resolve. j-scatter wins over i-scatter; both read ORIGINAL pos.
// Grid: 16 blocks x 256 threads.
// ---------------------------------------------------------------------------
__global__ __launch_bounds__(256) void combine_kernel(
    const float2* __restrict__ pos, const int* __restrict__ last_i,
    const int* __restrict__ last_j, const float2* __restrict__ ev,
    float2* __restrict__ out) {
  int b = blockIdx.x * blockDim.x + threadIdx.x;
  float2 p = pos[b];
  int lj = last_j[b], li = last_i[b];
  float2 o = p;
  if (lj >= 0) {
    o.x = __fsub_rn(p.x, __fmul_rn(0.5f, ev[lj].x));
    o.y = __fsub_rn(p.y, __fmul_rn(0.5f, ev[lj].y));
  } else if (li >= 0) {
    o.x = __fadd_rn(p.x, __fmul_rn(0.5f, ev[li].x));
    o.y = __fadd_rn(p.y, __fmul_rn(0.5f, ev[li].y));
  }
  out[b] = o;
}

// ---------------------------------------------------------------------------
extern "C" void kernel_launch(void* const* d_in, const int* in_sizes, int n_in,
                              void* d_out, int out_size, void* d_ws, size_t ws_size,
                              hipStream_t stream) {
  const float2* pos = (const float2*)d_in[0];
  const float* rad = (const float*)d_in[1];
  float2* out = (float2*)d_out;

  // Workspace layout (~2.3 MB of the ws).
  u64* masks = (u64*)d_ws;                              // NB*64 u64 = 2 MB
  float2* penvec = (float2*)(masks + (size_t)NB * 64);  // KBROAD float2
  float2* ev = penvec + KBROAD;                         // KEXACT float2
  int* row_counts = (int*)(ev + KEXACT);                // NB
  unsigned* pij = (unsigned*)(row_counts + NB);         // KBROAD
  unsigned* hitbits = pij + KBROAD;                     // 512
  int* last_i = (int*)(hitbits + 512);                  // NB
  int* last_j = last_i + NB;                            // NB

  count_kernel<<<512, 256, 0, stream>>>(pos, rad, row_counts, masks, hitbits,
                                        last_i, last_j);
  fill_kernel<<<256, 256, 0, stream>>>(pos, rad, row_counts, masks, penvec,
                                       pij, hitbits);
  exact_kernel<<<64, 256, 0, stream>>>(hitbits, pij, penvec, ev, last_i,
                                       last_j);
  combine_kernel<<<16, 256, 0, stream>>>(pos, last_i, last_j, ev, out);
}